// Round 15
// baseline (152.197 us; speedup 1.0000x reference)
//
#include <hip/hip_runtime.h>

#define BB 8
#define HH 96
#define WW 96
#define LL 9216
#define EPSF 1e-5f

typedef __attribute__((ext_vector_type(8))) short short8;
typedef __attribute__((ext_vector_type(4))) float f32x4;
typedef __attribute__((ext_vector_type(2))) float f32x2;
typedef __attribute__((ext_vector_type(4))) unsigned int uint32x4;
typedef unsigned short ushort_t;
typedef unsigned int uint32;

// silu via v_rcp_f32 (fp32 div is ~11 inst without fast-math; rcp is 1 inst,
// ~1ulp -- invisible after bf16 rounding)
__device__ __forceinline__ float silu_f(float x){
    return x * __builtin_amdgcn_rcpf(1.0f + __expf(-x));
}
__device__ __forceinline__ ushort_t f2bf(float f){
    uint32 u = __float_as_uint(f);
    u += 0x7FFFu + ((u >> 16) & 1u);          // RNE
    return (ushort_t)(u >> 16);
}
__device__ __forceinline__ float bf2f(short h){
    return __uint_as_float(((uint32)(ushort_t)h) << 16);
}
__device__ __forceinline__ uint32 pack2(float a, float b){
    return (uint32)f2bf(a) | ((uint32)f2bf(b) << 16);
}

// ---------------------------------------------------------------------------
// k_prep: W_in fp32 -> bf16 MFMA A-frag order; W_out folded with 0.25*gamma;
// bout2 = W_out @ beta + b_out (fp32, parallel); dwT[j][c] = dw_w[c][j].
// grid 128 x 256.
// ---------------------------------------------------------------------------
__global__ __launch_bounds__(256) void k_prep(const float* __restrict__ Win,
        const float* __restrict__ Wout, const float* __restrict__ dw_w,
        const float* __restrict__ gamma, const float* __restrict__ beta,
        const float* __restrict__ b_out,
        ushort_t* __restrict__ W2, ushort_t* __restrict__ WO2,
        float* __restrict__ dwT, float* __restrict__ bout2){
    int i = blockIdx.x * 256 + threadIdx.x;           // 0..32767
    {
        int e = i & 7, ln = (i >> 3) & 63, ks = (i >> 9) & 3, of = i >> 11;
        W2[i] = f2bf(Win[(of*16 + (ln & 15))*128 + ks*32 + (ln >> 4)*8 + e]);
    }
    if (i < 16384){
        int e = i & 7, ln = (i >> 3) & 63, ks = (i >> 9) & 3, of = i >> 11;
        int c = ks*32 + (ln >> 4)*8 + e;
        WO2[i] = f2bf(Wout[(of*16 + (ln & 15))*128 + c] * 0.25f * gamma[c]);
    }
    if (i < 896){
        int j = i >> 7, c = i & 127;
        dwT[i] = dw_w[c*7 + j];
    }
    if (blockIdx.x == 0){
        int o = threadIdx.x >> 1, half = threadIdx.x & 1;   // 2 thr per output
        float s = half ? 0.f : b_out[o];
        const float* wr = Wout + o * 128 + half * 64;
        const float* br = beta + half * 64;
        #pragma unroll 8
        for (int c = 0; c < 64; ++c) s = fmaf(wr[c], br[c], s);
        s += __shfl_xor(s, 1);
        if (!half) bout2[o] = s;
    }
}

// ---------------------------------------------------------------------------
// GEMM A: uv = W_in @ x + b_in, U = silu(uv[0:128]), V = uv[128:256].
// Output CHANNEL-major: UV[b][ch 0..255][L] bf16 (U = rows 0..127, V = 128..255).
// Wave wv owns o-frags {wv, wv+4, wv+8, wv+12} (interleaved silu balance).
// grid(144,B) x 256.
// ---------------------------------------------------------------------------
__global__ __launch_bounds__(256) void k_gemmA(const float* __restrict__ x,
        const ushort_t* __restrict__ W2, const float* __restrict__ b_in,
        ushort_t* __restrict__ UV){
    __shared__ __align__(16) char unia[34816];          // xt fp32 [128][65] | ec
    float (*xt)[65] = (float(*)[65])unia;
    ushort_t* ec = (ushort_t*)unia;                     // [256][68]
    __shared__ __align__(16) ushort_t xtile[64 * 128];  // swizzled token-major

    const int b = blockIdx.y, l0 = blockIdx.x * 64, tid = threadIdx.x;
    const int wv = tid >> 6, lane = tid & 63;
    const int lo = lane & 15, hi = lane >> 4;

    // stage x tile: float4 loads
    #pragma unroll
    for (int k = 0; k < 8; ++k){
        int idx = tid + k * 256;            // 0..2047
        int c = idx >> 4, col = (idx & 15) * 4;
        f32x4 v4 = *(const f32x4*)(x + ((size_t)(b * 128 + c)) * LL + l0 + col);
        xt[c][col + 0] = v4[0]; xt[c][col + 1] = v4[1];
        xt[c][col + 2] = v4[2]; xt[c][col + 3] = v4[3];
    }
    __syncthreads();
    #pragma unroll
    for (int p = 0; p < 16; ++p){
        int l = (tid >> 6) + p * 4;
        uint32 v = pack2(xt[2 * lane][l], xt[2 * lane + 1][l]);
        *(uint32*)((char*)xtile + l * 256 + ((lane * 4) ^ ((l & 7) << 4))) = v;
    }
    __syncthreads();

    const f32x4 zero = {0.f, 0.f, 0.f, 0.f};
    f32x4 acc[4][4];
    #pragma unroll
    for (int om = 0; om < 4; ++om)
        #pragma unroll
        for (int lf = 0; lf < 4; ++lf) acc[om][lf] = zero;

    #pragma unroll
    for (int ks = 0; ks < 4; ++ks){
        short8 af[4], bfr[4];
        #pragma unroll
        for (int om = 0; om < 4; ++om)
            af[om] = *(const short8*)(W2 + (size_t)(((om*4 + wv)*4 + ks)*64 + lane)*8);
        #pragma unroll
        for (int lf = 0; lf < 4; ++lf){
            int tok = lf * 16 + lo;
            bfr[lf] = *(const short8*)((char*)xtile + tok * 256 +
                        ((ks * 64 + hi * 16) ^ ((tok & 7) << 4)));
        }
        #pragma unroll
        for (int om = 0; om < 4; ++om)
            #pragma unroll
            for (int lf = 0; lf < 4; ++lf)
                acc[om][lf] = __builtin_amdgcn_mfma_f32_16x16x32_bf16(af[om], bfr[lf], acc[om][lf], 0, 0, 0);
    }
    __syncthreads();   // xt dead -> ec overlays

    #pragma unroll
    for (int om = 0; om < 4; ++om){
        int of = om * 4 + wv;                 // interleaved o-frag 0..15
        int obase = of * 16 + hi * 4;
        f32x4 bia = *(const f32x4*)(b_in + obase);
        const bool isU = (of < 8);
        #pragma unroll
        for (int lf = 0; lf < 4; ++lf){
            #pragma unroll
            for (int r = 0; r < 4; ++r){
                float v = acc[om][lf][r] + bia[r];
                if (isU) v = silu_f(v);
                ec[(obase + r) * 68 + lf * 16 + lo] = f2bf(v);
            }
        }
    }
    __syncthreads();

    const int r8 = tid >> 5, c32 = tid & 31;
    #pragma unroll
    for (int p = 0; p < 32; ++p){
        int row = r8 + p * 8;                 // 0..255
        int col = c32 * 2;
        uint32 v = *(const uint32*)(ec + row * 68 + col);
        *(uint32*)(UV + ((size_t)(b * 256 + row)) * LL + l0 + col) = v;
    }
}

// ---------------------------------------------------------------------------
// transposing butterfly over lane bits 0..2: afterwards lane holds the total
// of x[lane & 7] over its 8-lane group.
// ---------------------------------------------------------------------------
__device__ __forceinline__ float tbfly8(float (&x)[8], int lane){
    const int t0 = lane & 1, t1 = (lane >> 1) & 1, t2 = (lane >> 2) & 1;
    float y[4], z[2];
    #pragma unroll
    for (int j = 0; j < 4; ++j){
        float keep = t0 ? x[2*j+1] : x[2*j];
        float send = t0 ? x[2*j]   : x[2*j+1];
        y[j] = keep + __shfl_xor(send, 1);
    }
    #pragma unroll
    for (int j = 0; j < 2; ++j){
        float keep = t1 ? y[2*j+1] : y[2*j];
        float send = t1 ? y[2*j]   : y[2*j+1];
        z[j] = keep + __shfl_xor(send, 2);
    }
    float keep = t2 ? z[1] : z[0];
    float send = t2 ? z[0] : z[1];
    return keep + __shfl_xor(send, 4);
}

// ---------------------------------------------------------------------------
// Fused mixer + output GEMM. 512 thr = 8 waves; 32-token tile.
// cl = lane&15 (ch-in-wave), tg = lane>>4 (0..3), c0 = wv*16+cl, m8 = m0+tg*8.
// All tap loads upfront; both conv pairs in fp32 registers; ONE fused
// reduction; apply = sum_d y_d*r_d - C; ytile stores raw ysr (gamma/beta
// folded into WO2/bout2). 3 barriers total.
// __launch_bounds__(512, 8): raise residency floor to 8 waves/EU (VGPR cap
// 64; current use 60) -- mixout is TLP-starved at ~31% occupancy.
// grid(288, B) x 512, XCD-chunked swizzle.
// ---------------------------------------------------------------------------
__global__ __launch_bounds__(512, 8) void k_mixout(const ushort_t* __restrict__ UV,
        const float* __restrict__ dwT, const float* __restrict__ dw_b,
        const ushort_t* __restrict__ WO2, const float* __restrict__ bout2,
        float* __restrict__ out){
    __shared__ __align__(16) float red[8][32][8];       // 8 KB
    __shared__ float tot[32 * 6];                       // ra,rb,rc,rd,C per tok
    __shared__ __align__(16) char ytile[32 * 256];      // 8 KB swizzled

    // XCD-chunked swizzle over 2304 tiles
    const int flat = blockIdx.y * 288 + blockIdx.x;
    const int nf = (flat & 7) * 288 + (flat >> 3);
    const int b  = nf / 288;
    const int m0 = (nf % 288) * 32;

    const int tid  = threadIdx.x;
    const int lane = tid & 63;
    const int wv   = tid >> 6;           // 0..7
    const int cl   = lane & 15;
    const int tg   = lane >> 4;          // 0..3
    const int c0   = wv * 16 + cl;       // channel 0..127
    const int m8   = m0 + tg * 8;
    const int h    = m8 / WW;            // uniform over the 8 tokens
    const int w0g  = m8 - h * WW;

    const ushort_t* vrow = UV + ((size_t)(b * 256 + 128) + c0) * LL + m8;

    // ---- all global loads up front (latency hides under pair-1 compute) ----
    short8 u8  = *(const short8*)(UV + ((size_t)(b * 256) + c0) * LL + m8);
    short8 WBm = *(const short8*)(vrow);
    short8 WA  = *(const short8*)(vrow - 8);
    short8 WC  = *(const short8*)(vrow + 8);
    short8 g8[6];
    bool inb[6];
    #pragma unroll
    for (int r = 0; r < 6; ++r){
        const int dd = (r < 3) ? (r - 3) : (r - 2);
        const int hd = h + dd;
        inb[r] = (hd >= 0) && (hd < HH);
        g8[r] = *(const short8*)(vrow + 96 * dd);   // in ws bounds; gated by inb
    }
    float cw[7];
    #pragma unroll
    for (int j = 0; j < 7; ++j) cw[j] = dwT[j * 128 + c0];
    const float bias = dw_b[c0];

    float ya[8], yb[8], yc[8], yd[8];    // 4 directions, fp32 (no pack)
    float Sa, Qa, Sb, Qb, Sc, Qc, Sd, Qd;

    // ================= PAIR 1: lr + rl (flat H taps, register FIR) ==========
    {
        float f[14];
        #pragma unroll
        for (int k = 0; k < 14; ++k){
            int e = 5 + k;                 // elem m8-8+e = m8-3+k
            f[k] = bf2f(e < 8 ? WA[e] : (e < 16 ? WBm[e - 8] : WC[e - 16]));
        }
        if (m8 == 0){ f[0] = 0.f; f[1] = 0.f; f[2] = 0.f; }
        if (m8 == LL - 8){ f[11] = 0.f; f[12] = 0.f; f[13] = 0.f; }
        float qa[8], qb[8];
        #pragma unroll
        for (int i = 0; i < 8; ++i){
            float caf = bias, cbw = bias;
            #pragma unroll
            for (int j = 0; j < 7; ++j){
                caf = fmaf(cw[j],     f[i + j], caf);
                cbw = fmaf(cw[6 - j], f[i + j], cbw);
            }
            float uu = bf2f(u8[i]);
            ya[i] = uu * silu_f(caf);
            yb[i] = uu * silu_f(cbw);
            qa[i] = ya[i] * ya[i];
            qb[i] = yb[i] * yb[i];
        }
        Sa = tbfly8(ya, lane); Sa += __shfl_xor(Sa, 8);
        Qa = tbfly8(qa, lane); Qa += __shfl_xor(Qa, 8);
        Sb = tbfly8(yb, lane); Sb += __shfl_xor(Sb, 8);
        Qb = tbfly8(qb, lane); Qb += __shfl_xor(Qb, 8);
    }

    // ================= PAIR 2: tb + bt (vertical taps) ======================
    {
        float caf[8], cbw[8];
        #pragma unroll
        for (int i = 0; i < 8; ++i){
            float v0 = bf2f(WBm[i]);               // d = 0 tap
            caf[i] = fmaf(cw[3], v0, bias);
            cbw[i] = caf[i];
        }
        #pragma unroll
        for (int r = 0; r < 6; ++r){
            const int dd = (r < 3) ? (r - 3) : (r - 2);
            const int j  = dd + 3;
            float gv[8];
            if (inb[r]){
                #pragma unroll
                for (int i = 0; i < 8; ++i) gv[i] = bf2f(g8[r][i]);
            } else {
                const int hd = h + dd;
                const int del = (hd < 0) ? (LL - 1) : (1 - LL);
                #pragma unroll
                for (int i = 0; i < 8; ++i){
                    int q = (w0g + i) * HH + hd;   // col-major flat pos
                    bool ok = (unsigned)q < (unsigned)LL;
                    gv[i] = ok ? bf2f(vrow[96 * dd + del + i]) : 0.f;
                }
            }
            #pragma unroll
            for (int i = 0; i < 8; ++i){
                caf[i] = fmaf(cw[j],     gv[i], caf[i]);
                cbw[i] = fmaf(cw[6 - j], gv[i], cbw[i]);
            }
        }
        float qc[8], qd[8];
        #pragma unroll
        for (int i = 0; i < 8; ++i){
            float uu = bf2f(u8[i]);
            yc[i] = uu * silu_f(caf[i]);
            yd[i] = uu * silu_f(cbw[i]);
            qc[i] = yc[i] * yc[i];
            qd[i] = yd[i] * yd[i];
        }
        Sc = tbfly8(yc, lane); Sc += __shfl_xor(Sc, 8);
        Qc = tbfly8(qc, lane); Qc += __shfl_xor(Qc, 8);
        Sd = tbfly8(yd, lane); Sd += __shfl_xor(Sd, 8);
        Qd = tbfly8(qd, lane); Qd += __shfl_xor(Qd, 8);
    }

    // ---- single fused reduction --------------------------------------------
    {
        const int tok32 = tg * 8 + (lane & 7);
        const int halfp = (lane >> 3) & 1;       // duplicate lanes split pairs
        f32x4 stv;
        if (halfp){ stv[0] = Sc; stv[1] = Qc; stv[2] = Sd; stv[3] = Qd; }
        else      { stv[0] = Sa; stv[1] = Qa; stv[2] = Sb; stv[3] = Qb; }
        *(f32x4*)(&red[wv][tok32][halfp * 4]) = stv;
    }
    __syncthreads();
    if (tid < 32){
        f32x4 s0 = {0.f, 0.f, 0.f, 0.f}, s1 = {0.f, 0.f, 0.f, 0.f};
        #pragma unroll
        for (int w2 = 0; w2 < 8; ++w2){
            s0 += *(const f32x4*)(&red[w2][tid][0]);
            s1 += *(const f32x4*)(&red[w2][tid][4]);
        }
        const float inv = 1.f / 128.f;
        float mua = s0[0] * inv, ra = __builtin_amdgcn_rsqf(s0[1] * inv - mua * mua + EPSF);
        float mub = s0[2] * inv, rb = __builtin_amdgcn_rsqf(s0[3] * inv - mub * mub + EPSF);
        float muc = s1[0] * inv, rc = __builtin_amdgcn_rsqf(s1[1] * inv - muc * muc + EPSF);
        float mud = s1[2] * inv, rd = __builtin_amdgcn_rsqf(s1[3] * inv - mud * mud + EPSF);
        float C = mua * ra + mub * rb + muc * rc + mud * rd;
        tot[tid * 6 + 0] = ra; tot[tid * 6 + 1] = rb;
        tot[tid * 6 + 2] = rc; tot[tid * 6 + 3] = rd;
        tot[tid * 6 + 4] = C;
    }
    __syncthreads();

    // ---- apply (gamma/beta folded into WO2/bout2) + ytile ------------------
    {
        #pragma unroll
        for (int i = 0; i < 8; ++i){
            int tok = tg * 8 + i;
            f32x2 r01 = *(const f32x2*)(&tot[tok * 6 + 0]);
            f32x2 r23 = *(const f32x2*)(&tot[tok * 6 + 2]);
            float C   = tot[tok * 6 + 4];
            float v = fmaf(ya[i], r01[0], fmaf(yb[i], r01[1],
                      fmaf(yc[i], r23[0], fmaf(yd[i], r23[1], -C))));
            int swz = ((tok & 7) ^ (tok >> 3)) << 4;
            *(ushort_t*)(ytile + tok * 256 + ((c0 * 2) ^ swz)) = f2bf(v);
        }
    }
    __syncthreads();

    // ---- Phase 2: output GEMM (8 waves: wave = 16-o frag x 32 tok) ---------
    const int lo = lane & 15, hi = lane >> 4;
    const int ow = wv;                    // o-range [16*ow, 16*ow+16)
    const f32x4 zero = {0.f, 0.f, 0.f, 0.f};
    f32x4 acc[2] = {zero, zero};
    #pragma unroll
    for (int ks = 0; ks < 4; ++ks){
        short8 af = *(const short8*)(WO2 + (size_t)((ow * 4 + ks) * 64 + lane) * 8);
        #pragma unroll
        for (int t2 = 0; t2 < 2; ++t2){
            int tok = t2 * 16 + lo;
            int swz = ((tok & 7) ^ (tok >> 3)) << 4;
            short8 bfr = *(const short8*)(ytile + tok * 256 +
                            ((ks * 64 + hi * 16) ^ swz));
            acc[t2] = __builtin_amdgcn_mfma_f32_16x16x32_bf16(af, bfr, acc[t2], 0, 0, 0);
        }
    }
    {
        f32x4 bia = *(const f32x4*)(bout2 + ow * 16 + hi * 4);
        #pragma unroll
        for (int t2 = 0; t2 < 2; ++t2){
            int l = m0 + t2 * 16 + lo;
            #pragma unroll
            for (int r = 0; r < 4; ++r){
                int o = ow * 16 + hi * 4 + r;
                out[((size_t)(b * 128 + o)) * LL + l] = acc[t2][r] + bia[r];
            }
        }
    }
}

// ---------------------------------------------------------------------------
extern "C" void kernel_launch(void* const* d_in, const int* in_sizes, int n_in,
                              void* d_out, int out_size, void* d_ws, size_t ws_size,
                              hipStream_t stream) {
    const float* x     = (const float*)d_in[0];
    const float* W_in  = (const float*)d_in[1];
    const float* b_in  = (const float*)d_in[2];
    const float* dw_w  = (const float*)d_in[3];
    const float* dw_b  = (const float*)d_in[4];
    const float* gamma = (const float*)d_in[5];
    const float* beta  = (const float*)d_in[6];
    const float* W_out = (const float*)d_in[7];
    const float* b_out = (const float*)d_in[8];
    float* out = (float*)d_out;

    // ws layout: UV (B,256,L) bf16 | 64B guard | W2 frag | WO2 frag | dwT | bout2
    ushort_t* UV    = (ushort_t*)d_ws;                     // 37,748,736 B
    ushort_t* W2    = UV + (size_t)BB * 256 * LL + 32;     // 256x128 bf16 frag
    ushort_t* WO2   = W2 + 256 * 128;                      // 128x128 bf16 frag
    float*    dwT   = (float*)(WO2 + 128 * 128);           // [7][128] fp32
    float*    bout2 = dwT + 896;                           // [128] fp32

    k_prep<<<128, 256, 0, stream>>>(W_in, W_out, dw_w, gamma, beta, b_out,
                                    W2, WO2, dwT, bout2);

    dim3 gA(LL / 64, BB);
    k_gemmA<<<gA, 256, 0, stream>>>(x, W2, b_in, UV);

    dim3 gM(288, BB);
    k_mixout<<<gM, 512, 0, stream>>>(UV, dwT, dw_b, WO2, bout2, out);
}

// Round 16
// 77.522 us; speedup vs baseline: 1.9633x; 1.9633x over previous
//
#include <hip/hip_runtime.h>

#define BB 8
#define HH 96
#define WW 96
#define LL 9216
#define EPSF 1e-5f

typedef __attribute__((ext_vector_type(8))) short short8;
typedef __attribute__((ext_vector_type(4))) float f32x4;
typedef __attribute__((ext_vector_type(2))) float f32x2;
typedef __attribute__((ext_vector_type(4))) unsigned int uint32x4;
typedef unsigned short ushort_t;
typedef unsigned int uint32;

// silu via v_rcp_f32 (fp32 div is ~11 inst without fast-math; rcp is 1 inst,
// ~1ulp -- invisible after bf16 rounding)
__device__ __forceinline__ float silu_f(float x){
    return x * __builtin_amdgcn_rcpf(1.0f + __expf(-x));
}
__device__ __forceinline__ ushort_t f2bf(float f){
    uint32 u = __float_as_uint(f);
    u += 0x7FFFu + ((u >> 16) & 1u);          // RNE
    return (ushort_t)(u >> 16);
}
__device__ __forceinline__ float bf2f(short h){
    return __uint_as_float(((uint32)(ushort_t)h) << 16);
}
__device__ __forceinline__ uint32 pack2(float a, float b){
    return (uint32)f2bf(a) | ((uint32)f2bf(b) << 16);
}

// ---------------------------------------------------------------------------
// k_prep: W_in fp32 -> bf16 MFMA A-frag order; W_out folded with 0.25*gamma;
// bout2 = W_out @ beta + b_out (fp32, parallel); dwT[j][c] = dw_w[c][j].
// grid 128 x 256.
// ---------------------------------------------------------------------------
__global__ __launch_bounds__(256) void k_prep(const float* __restrict__ Win,
        const float* __restrict__ Wout, const float* __restrict__ dw_w,
        const float* __restrict__ gamma, const float* __restrict__ beta,
        const float* __restrict__ b_out,
        ushort_t* __restrict__ W2, ushort_t* __restrict__ WO2,
        float* __restrict__ dwT, float* __restrict__ bout2){
    int i = blockIdx.x * 256 + threadIdx.x;           // 0..32767
    {
        int e = i & 7, ln = (i >> 3) & 63, ks = (i >> 9) & 3, of = i >> 11;
        W2[i] = f2bf(Win[(of*16 + (ln & 15))*128 + ks*32 + (ln >> 4)*8 + e]);
    }
    if (i < 16384){
        int e = i & 7, ln = (i >> 3) & 63, ks = (i >> 9) & 3, of = i >> 11;
        int c = ks*32 + (ln >> 4)*8 + e;
        WO2[i] = f2bf(Wout[(of*16 + (ln & 15))*128 + c] * 0.25f * gamma[c]);
    }
    if (i < 896){
        int j = i >> 7, c = i & 127;
        dwT[i] = dw_w[c*7 + j];
    }
    if (blockIdx.x == 0){
        int o = threadIdx.x >> 1, half = threadIdx.x & 1;   // 2 thr per output
        float s = half ? 0.f : b_out[o];
        const float* wr = Wout + o * 128 + half * 64;
        const float* br = beta + half * 64;
        #pragma unroll 8
        for (int c = 0; c < 64; ++c) s = fmaf(wr[c], br[c], s);
        s += __shfl_xor(s, 1);
        if (!half) bout2[o] = s;
    }
}

// ---------------------------------------------------------------------------
// GEMM A: uv = W_in @ x + b_in, U = silu(uv[0:128]), V = uv[128:256].
// Output CHANNEL-major: UV[b][ch 0..255][L] bf16 (U = rows 0..127, V = 128..255).
// grid(144,B) x 256.   (round-13 configuration -- measured best)
// ---------------------------------------------------------------------------
__global__ __launch_bounds__(256) void k_gemmA(const float* __restrict__ x,
        const ushort_t* __restrict__ W2, const float* __restrict__ b_in,
        ushort_t* __restrict__ UV){
    __shared__ __align__(16) char unia[34816];          // xt fp32 [128][65] | ec
    float (*xt)[65] = (float(*)[65])unia;
    ushort_t* ec = (ushort_t*)unia;                     // [256][68]
    __shared__ __align__(16) ushort_t xtile[64 * 128];  // swizzled token-major

    const int b = blockIdx.y, l0 = blockIdx.x * 64, tid = threadIdx.x;
    const int wv = tid >> 6, lane = tid & 63;
    const int lo = lane & 15, hi = lane >> 4;

    #pragma unroll
    for (int k = 0; k < 32; ++k){
        int c = (tid >> 6) + k * 4;
        xt[c][lane] = x[((size_t)(b * 128 + c)) * LL + l0 + lane];
    }
    __syncthreads();
    #pragma unroll
    for (int p = 0; p < 16; ++p){
        int l = (tid >> 6) + p * 4;
        uint32 v = pack2(xt[2 * lane][l], xt[2 * lane + 1][l]);
        *(uint32*)((char*)xtile + l * 256 + ((lane * 4) ^ ((l & 7) << 4))) = v;
    }
    __syncthreads();

    const f32x4 zero = {0.f, 0.f, 0.f, 0.f};
    f32x4 acc[4][4];
    #pragma unroll
    for (int om = 0; om < 4; ++om)
        #pragma unroll
        for (int lf = 0; lf < 4; ++lf) acc[om][lf] = zero;

    #pragma unroll
    for (int ks = 0; ks < 4; ++ks){
        short8 af[4], bfr[4];
        #pragma unroll
        for (int om = 0; om < 4; ++om)
            af[om] = *(const short8*)(W2 + (size_t)(((wv*4 + om)*4 + ks)*64 + lane)*8);
        #pragma unroll
        for (int lf = 0; lf < 4; ++lf){
            int tok = lf * 16 + lo;
            bfr[lf] = *(const short8*)((char*)xtile + tok * 256 +
                        ((ks * 64 + hi * 16) ^ ((tok & 7) << 4)));
        }
        #pragma unroll
        for (int om = 0; om < 4; ++om)
            #pragma unroll
            for (int lf = 0; lf < 4; ++lf)
                acc[om][lf] = __builtin_amdgcn_mfma_f32_16x16x32_bf16(af[om], bfr[lf], acc[om][lf], 0, 0, 0);
    }
    __syncthreads();   // xt dead -> ec overlays

    #pragma unroll
    for (int om = 0; om < 4; ++om){
        int obase = wv * 64 + om * 16 + hi * 4;
        f32x4 bia = *(const f32x4*)(b_in + obase);
        const bool isU = (wv < 2);
        #pragma unroll
        for (int lf = 0; lf < 4; ++lf){
            #pragma unroll
            for (int r = 0; r < 4; ++r){
                float v = acc[om][lf][r] + bia[r];
                if (isU) v = silu_f(v);
                ec[(obase + r) * 68 + lf * 16 + lo] = f2bf(v);
            }
        }
    }
    __syncthreads();

    const int r8 = tid >> 5, c32 = tid & 31;
    #pragma unroll
    for (int p = 0; p < 32; ++p){
        int row = r8 + p * 8;                 // 0..255
        int col = c32 * 2;
        uint32 v = *(const uint32*)(ec + row * 68 + col);
        *(uint32*)(UV + ((size_t)(b * 256 + row)) * LL + l0 + col) = v;
    }
}

// ---------------------------------------------------------------------------
// transposing butterfly over lane bits 0..2: afterwards lane holds the total
// of x[lane & 7] over its 8-lane group.
// ---------------------------------------------------------------------------
__device__ __forceinline__ float tbfly8(float (&x)[8], int lane){
    const int t0 = lane & 1, t1 = (lane >> 1) & 1, t2 = (lane >> 2) & 1;
    float y[4], z[2];
    #pragma unroll
    for (int j = 0; j < 4; ++j){
        float keep = t0 ? x[2*j+1] : x[2*j];
        float send = t0 ? x[2*j]   : x[2*j+1];
        y[j] = keep + __shfl_xor(send, 1);
    }
    #pragma unroll
    for (int j = 0; j < 2; ++j){
        float keep = t1 ? y[2*j+1] : y[2*j];
        float send = t1 ? y[2*j]   : y[2*j+1];
        z[j] = keep + __shfl_xor(send, 2);
    }
    float keep = t2 ? z[1] : z[0];
    float send = t2 ? z[0] : z[1];
    return keep + __shfl_xor(send, 4);
}

// ---------------------------------------------------------------------------
// Fused mixer + output GEMM. 512 thr = 8 waves; 32-token tile.
// cl = lane&15 (ch-in-wave), tg = lane>>4 (0..3), c0 = wv*16+cl, m8 = m0+tg*8.
// All tap loads upfront; both conv pairs in fp32 registers; ONE fused
// reduction; apply = sum_d y_d*r_d - C; ytile stores raw ysr (gamma/beta
// folded into WO2/bout2). WO2 fragments prefetched before the apply phase
// so the out-GEMM doesn't stall on L2 after the last barrier. 3 barriers.
// grid(288, B) x 512, XCD-chunked swizzle.  __launch_bounds__(512,4) --
// (512,8) forces VGPR=32 and spills catastrophically (round-15 lesson).
// ---------------------------------------------------------------------------
__global__ __launch_bounds__(512, 4) void k_mixout(const ushort_t* __restrict__ UV,
        const float* __restrict__ dwT, const float* __restrict__ dw_b,
        const ushort_t* __restrict__ WO2, const float* __restrict__ bout2,
        float* __restrict__ out){
    __shared__ __align__(16) float red[8][32][8];       // 8 KB
    __shared__ float tot[32 * 6];                       // ra,rb,rc,rd,C per tok
    __shared__ __align__(16) char ytile[32 * 256];      // 8 KB swizzled

    // XCD-chunked swizzle over 2304 tiles
    const int flat = blockIdx.y * 288 + blockIdx.x;
    const int nf = (flat & 7) * 288 + (flat >> 3);
    const int b  = nf / 288;
    const int m0 = (nf % 288) * 32;

    const int tid  = threadIdx.x;
    const int lane = tid & 63;
    const int wv   = tid >> 6;           // 0..7
    const int cl   = lane & 15;
    const int tg   = lane >> 4;          // 0..3
    const int c0   = wv * 16 + cl;       // channel 0..127
    const int m8   = m0 + tg * 8;
    const int h    = m8 / WW;            // uniform over the 8 tokens
    const int w0g  = m8 - h * WW;

    const ushort_t* vrow = UV + ((size_t)(b * 256 + 128) + c0) * LL + m8;

    // ---- all global loads up front (latency hides under pair-1 compute) ----
    short8 u8  = *(const short8*)(UV + ((size_t)(b * 256) + c0) * LL + m8);
    short8 WBm = *(const short8*)(vrow);
    short8 WA  = *(const short8*)(vrow - 8);
    short8 WC  = *(const short8*)(vrow + 8);
    short8 g8[6];
    bool inb[6];
    #pragma unroll
    for (int r = 0; r < 6; ++r){
        const int dd = (r < 3) ? (r - 3) : (r - 2);
        const int hd = h + dd;
        inb[r] = (hd >= 0) && (hd < HH);
        g8[r] = *(const short8*)(vrow + 96 * dd);   // in ws bounds; gated by inb
    }
    float cw[7];
    #pragma unroll
    for (int j = 0; j < 7; ++j) cw[j] = dwT[j * 128 + c0];
    const float bias = dw_b[c0];

    float ya[8], yb[8], yc[8], yd[8];    // 4 directions, fp32 (no pack)
    float Sa, Qa, Sb, Qb, Sc, Qc, Sd, Qd;

    // ================= PAIR 1: lr + rl (flat H taps, register FIR) ==========
    {
        float f[14];
        #pragma unroll
        for (int k = 0; k < 14; ++k){
            int e = 5 + k;                 // elem m8-8+e = m8-3+k
            f[k] = bf2f(e < 8 ? WA[e] : (e < 16 ? WBm[e - 8] : WC[e - 16]));
        }
        if (m8 == 0){ f[0] = 0.f; f[1] = 0.f; f[2] = 0.f; }
        if (m8 == LL - 8){ f[11] = 0.f; f[12] = 0.f; f[13] = 0.f; }
        float qa[8], qb[8];
        #pragma unroll
        for (int i = 0; i < 8; ++i){
            float caf = bias, cbw = bias;
            #pragma unroll
            for (int j = 0; j < 7; ++j){
                caf = fmaf(cw[j],     f[i + j], caf);
                cbw = fmaf(cw[6 - j], f[i + j], cbw);
            }
            float uu = bf2f(u8[i]);
            ya[i] = uu * silu_f(caf);
            yb[i] = uu * silu_f(cbw);
            qa[i] = ya[i] * ya[i];
            qb[i] = yb[i] * yb[i];
        }
        Sa = tbfly8(ya, lane); Sa += __shfl_xor(Sa, 8);
        Qa = tbfly8(qa, lane); Qa += __shfl_xor(Qa, 8);
        Sb = tbfly8(yb, lane); Sb += __shfl_xor(Sb, 8);
        Qb = tbfly8(qb, lane); Qb += __shfl_xor(Qb, 8);
    }

    // ================= PAIR 2: tb + bt (vertical taps) ======================
    {
        float caf[8], cbw[8];
        #pragma unroll
        for (int i = 0; i < 8; ++i){
            float v0 = bf2f(WBm[i]);               // d = 0 tap
            caf[i] = fmaf(cw[3], v0, bias);
            cbw[i] = caf[i];
        }
        #pragma unroll
        for (int r = 0; r < 6; ++r){
            const int dd = (r < 3) ? (r - 3) : (r - 2);
            const int j  = dd + 3;
            float gv[8];
            if (inb[r]){
                #pragma unroll
                for (int i = 0; i < 8; ++i) gv[i] = bf2f(g8[r][i]);
            } else {
                const int hd = h + dd;
                const int del = (hd < 0) ? (LL - 1) : (1 - LL);
                #pragma unroll
                for (int i = 0; i < 8; ++i){
                    int q = (w0g + i) * HH + hd;   // col-major flat pos
                    bool ok = (unsigned)q < (unsigned)LL;
                    gv[i] = ok ? bf2f(vrow[96 * dd + del + i]) : 0.f;
                }
            }
            #pragma unroll
            for (int i = 0; i < 8; ++i){
                caf[i] = fmaf(cw[j],     gv[i], caf[i]);
                cbw[i] = fmaf(cw[6 - j], gv[i], cbw[i]);
            }
        }
        float qc[8], qd[8];
        #pragma unroll
        for (int i = 0; i < 8; ++i){
            float uu = bf2f(u8[i]);
            yc[i] = uu * silu_f(caf[i]);
            yd[i] = uu * silu_f(cbw[i]);
            qc[i] = yc[i] * yc[i];
            qd[i] = yd[i] * yd[i];
        }
        Sc = tbfly8(yc, lane); Sc += __shfl_xor(Sc, 8);
        Qc = tbfly8(qc, lane); Qc += __shfl_xor(Qc, 8);
        Sd = tbfly8(yd, lane); Sd += __shfl_xor(Sd, 8);
        Qd = tbfly8(qd, lane); Qd += __shfl_xor(Qd, 8);
    }

    // ---- single fused reduction --------------------------------------------
    {
        const int tok32 = tg * 8 + (lane & 7);
        const int halfp = (lane >> 3) & 1;       // duplicate lanes split pairs
        f32x4 stv;
        if (halfp){ stv[0] = Sc; stv[1] = Qc; stv[2] = Sd; stv[3] = Qd; }
        else      { stv[0] = Sa; stv[1] = Qa; stv[2] = Sb; stv[3] = Qb; }
        *(f32x4*)(&red[wv][tok32][halfp * 4]) = stv;
    }
    __syncthreads();
    if (tid < 32){
        f32x4 s0 = {0.f, 0.f, 0.f, 0.f}, s1 = {0.f, 0.f, 0.f, 0.f};
        #pragma unroll
        for (int w2 = 0; w2 < 8; ++w2){
            s0 += *(const f32x4*)(&red[w2][tid][0]);
            s1 += *(const f32x4*)(&red[w2][tid][4]);
        }
        const float inv = 1.f / 128.f;
        float mua = s0[0] * inv, ra = __builtin_amdgcn_rsqf(s0[1] * inv - mua * mua + EPSF);
        float mub = s0[2] * inv, rb = __builtin_amdgcn_rsqf(s0[3] * inv - mub * mub + EPSF);
        float muc = s1[0] * inv, rc = __builtin_amdgcn_rsqf(s1[1] * inv - muc * muc + EPSF);
        float mud = s1[2] * inv, rd = __builtin_amdgcn_rsqf(s1[3] * inv - mud * mud + EPSF);
        float C = mua * ra + mub * rb + muc * rc + mud * rd;
        tot[tid * 6 + 0] = ra; tot[tid * 6 + 1] = rb;
        tot[tid * 6 + 2] = rc; tot[tid * 6 + 3] = rd;
        tot[tid * 6 + 4] = C;
    }
    __syncthreads();

    // ---- prefetch out-GEMM operands (L2-resident; hides under apply) -------
    const int ow = wv;                    // o-range [16*ow, 16*ow+16)
    const int lo = lane & 15, hi = lane >> 4;
    short8 afp[4];
    #pragma unroll
    for (int ks = 0; ks < 4; ++ks)
        afp[ks] = *(const short8*)(WO2 + (size_t)((ow * 4 + ks) * 64 + lane) * 8);
    f32x4 bia = *(const f32x4*)(bout2 + ow * 16 + hi * 4);

    // ---- apply (gamma/beta folded into WO2/bout2) + ytile ------------------
    {
        #pragma unroll
        for (int i = 0; i < 8; ++i){
            int tok = tg * 8 + i;
            f32x2 r01 = *(const f32x2*)(&tot[tok * 6 + 0]);
            f32x2 r23 = *(const f32x2*)(&tot[tok * 6 + 2]);
            float C   = tot[tok * 6 + 4];
            float v = fmaf(ya[i], r01[0], fmaf(yb[i], r01[1],
                      fmaf(yc[i], r23[0], fmaf(yd[i], r23[1], -C))));
            int swz = ((tok & 7) ^ (tok >> 3)) << 4;
            *(ushort_t*)(ytile + tok * 256 + ((c0 * 2) ^ swz)) = f2bf(v);
        }
    }
    __syncthreads();

    // ---- Phase 2: output GEMM (8 waves: wave = 16-o frag x 32 tok) ---------
    const f32x4 zero = {0.f, 0.f, 0.f, 0.f};
    f32x4 acc[2] = {zero, zero};
    #pragma unroll
    for (int ks = 0; ks < 4; ++ks){
        #pragma unroll
        for (int t2 = 0; t2 < 2; ++t2){
            int tok = t2 * 16 + lo;
            int swz = ((tok & 7) ^ (tok >> 3)) << 4;
            short8 bfr = *(const short8*)(ytile + tok * 256 +
                            ((ks * 64 + hi * 16) ^ swz));
            acc[t2] = __builtin_amdgcn_mfma_f32_16x16x32_bf16(afp[ks], bfr, acc[t2], 0, 0, 0);
        }
    }
    {
        #pragma unroll
        for (int t2 = 0; t2 < 2; ++t2){
            int l = m0 + t2 * 16 + lo;
            #pragma unroll
            for (int r = 0; r < 4; ++r){
                int o = ow * 16 + hi * 4 + r;
                out[((size_t)(b * 128 + o)) * LL + l] = acc[t2][r] + bia[r];
            }
        }
    }
}

// ---------------------------------------------------------------------------
extern "C" void kernel_launch(void* const* d_in, const int* in_sizes, int n_in,
                              void* d_out, int out_size, void* d_ws, size_t ws_size,
                              hipStream_t stream) {
    const float* x     = (const float*)d_in[0];
    const float* W_in  = (const float*)d_in[1];
    const float* b_in  = (const float*)d_in[2];
    const float* dw_w  = (const float*)d_in[3];
    const float* dw_b  = (const float*)d_in[4];
    const float* gamma = (const float*)d_in[5];
    const float* beta  = (const float*)d_in[6];
    const float* W_out = (const float*)d_in[7];
    const float* b_out = (const float*)d_in[8];
    float* out = (float*)d_out;

    // ws layout: UV (B,256,L) bf16 | 64B guard | W2 frag | WO2 frag | dwT | bout2
    ushort_t* UV    = (ushort_t*)d_ws;                     // 37,748,736 B
    ushort_t* W2    = UV + (size_t)BB * 256 * LL + 32;     // 256x128 bf16 frag
    ushort_t* WO2   = W2 + 256 * 128;                      // 128x128 bf16 frag
    float*    dwT   = (float*)(WO2 + 128 * 128);           // [7][128] fp32
    float*    bout2 = dwT + 896;                           // [128] fp32

    k_prep<<<128, 256, 0, stream>>>(W_in, W_out, dw_w, gamma, beta, b_out,
                                    W2, WO2, dwT, bout2);

    dim3 gA(LL / 64, BB);
    k_gemmA<<<gA, 256, 0, stream>>>(x, W2, b_in, UV);

    dim3 gM(288, BB);
    k_mixout<<<gM, 512, 0, stream>>>(UV, dwT, dw_b, WO2, bout2, out);
}

// Round 17
// 77.109 us; speedup vs baseline: 1.9738x; 1.0054x over previous
//
#include <hip/hip_runtime.h>

#define BB 8
#define HH 96
#define WW 96
#define LL 9216
#define EPSF 1e-5f

typedef __attribute__((ext_vector_type(8))) short short8;
typedef __attribute__((ext_vector_type(4))) float f32x4;
typedef __attribute__((ext_vector_type(2))) float f32x2;
typedef __attribute__((ext_vector_type(4))) unsigned int uint32x4;
typedef unsigned short ushort_t;
typedef unsigned int uint32;

// silu via v_rcp_f32 (fp32 div is ~11 inst without fast-math; rcp is 1 inst,
// ~1ulp -- invisible after bf16 rounding)
__device__ __forceinline__ float silu_f(float x){
    return x * __builtin_amdgcn_rcpf(1.0f + __expf(-x));
}
__device__ __forceinline__ ushort_t f2bf(float f){
    uint32 u = __float_as_uint(f);
    u += 0x7FFFu + ((u >> 16) & 1u);          // RNE
    return (ushort_t)(u >> 16);
}
__device__ __forceinline__ float bf2f(short h){
    return __uint_as_float(((uint32)(ushort_t)h) << 16);
}
__device__ __forceinline__ uint32 pack2(float a, float b){
    return (uint32)f2bf(a) | ((uint32)f2bf(b) << 16);
}

// ---------------------------------------------------------------------------
// k_prep: W_in fp32 -> bf16 MFMA A-frag order; W_out folded with 0.25*gamma;
// bout2 = W_out @ beta + b_out (fp32, parallel); dwT[j][c] = dw_w[c][j].
// grid 128 x 256.
// ---------------------------------------------------------------------------
__global__ __launch_bounds__(256) void k_prep(const float* __restrict__ Win,
        const float* __restrict__ Wout, const float* __restrict__ dw_w,
        const float* __restrict__ gamma, const float* __restrict__ beta,
        const float* __restrict__ b_out,
        ushort_t* __restrict__ W2, ushort_t* __restrict__ WO2,
        float* __restrict__ dwT, float* __restrict__ bout2){
    int i = blockIdx.x * 256 + threadIdx.x;           // 0..32767
    {
        int e = i & 7, ln = (i >> 3) & 63, ks = (i >> 9) & 3, of = i >> 11;
        W2[i] = f2bf(Win[(of*16 + (ln & 15))*128 + ks*32 + (ln >> 4)*8 + e]);
    }
    if (i < 16384){
        int e = i & 7, ln = (i >> 3) & 63, ks = (i >> 9) & 3, of = i >> 11;
        int c = ks*32 + (ln >> 4)*8 + e;
        WO2[i] = f2bf(Wout[(of*16 + (ln & 15))*128 + c] * 0.25f * gamma[c]);
    }
    if (i < 896){
        int j = i >> 7, c = i & 127;
        dwT[i] = dw_w[c*7 + j];
    }
    if (blockIdx.x == 0){
        int o = threadIdx.x >> 1, half = threadIdx.x & 1;   // 2 thr per output
        float s = half ? 0.f : b_out[o];
        const float* wr = Wout + o * 128 + half * 64;
        const float* br = beta + half * 64;
        #pragma unroll 8
        for (int c = 0; c < 64; ++c) s = fmaf(wr[c], br[c], s);
        s += __shfl_xor(s, 1);
        if (!half) bout2[o] = s;
    }
}

// ---------------------------------------------------------------------------
// GEMM A: uv = W_in @ x + b_in, U = silu(uv[0:128]), V = uv[128:256].
// Output CHANNEL-major: UV[b][ch 0..255][L] bf16 (U = rows 0..127, V = 128..255).
// grid(144,B) x 256.   (round-13 configuration -- measured best)
// ---------------------------------------------------------------------------
__global__ __launch_bounds__(256) void k_gemmA(const float* __restrict__ x,
        const ushort_t* __restrict__ W2, const float* __restrict__ b_in,
        ushort_t* __restrict__ UV){
    __shared__ __align__(16) char unia[34816];          // xt fp32 [128][65] | ec
    float (*xt)[65] = (float(*)[65])unia;
    ushort_t* ec = (ushort_t*)unia;                     // [256][68]
    __shared__ __align__(16) ushort_t xtile[64 * 128];  // swizzled token-major

    const int b = blockIdx.y, l0 = blockIdx.x * 64, tid = threadIdx.x;
    const int wv = tid >> 6, lane = tid & 63;
    const int lo = lane & 15, hi = lane >> 4;

    #pragma unroll
    for (int k = 0; k < 32; ++k){
        int c = (tid >> 6) + k * 4;
        xt[c][lane] = x[((size_t)(b * 128 + c)) * LL + l0 + lane];
    }
    __syncthreads();
    #pragma unroll
    for (int p = 0; p < 16; ++p){
        int l = (tid >> 6) + p * 4;
        uint32 v = pack2(xt[2 * lane][l], xt[2 * lane + 1][l]);
        *(uint32*)((char*)xtile + l * 256 + ((lane * 4) ^ ((l & 7) << 4))) = v;
    }
    __syncthreads();

    const f32x4 zero = {0.f, 0.f, 0.f, 0.f};
    f32x4 acc[4][4];
    #pragma unroll
    for (int om = 0; om < 4; ++om)
        #pragma unroll
        for (int lf = 0; lf < 4; ++lf) acc[om][lf] = zero;

    #pragma unroll
    for (int ks = 0; ks < 4; ++ks){
        short8 af[4], bfr[4];
        #pragma unroll
        for (int om = 0; om < 4; ++om)
            af[om] = *(const short8*)(W2 + (size_t)(((wv*4 + om)*4 + ks)*64 + lane)*8);
        #pragma unroll
        for (int lf = 0; lf < 4; ++lf){
            int tok = lf * 16 + lo;
            bfr[lf] = *(const short8*)((char*)xtile + tok * 256 +
                        ((ks * 64 + hi * 16) ^ ((tok & 7) << 4)));
        }
        #pragma unroll
        for (int om = 0; om < 4; ++om)
            #pragma unroll
            for (int lf = 0; lf < 4; ++lf)
                acc[om][lf] = __builtin_amdgcn_mfma_f32_16x16x32_bf16(af[om], bfr[lf], acc[om][lf], 0, 0, 0);
    }
    __syncthreads();   // xt dead -> ec overlays

    #pragma unroll
    for (int om = 0; om < 4; ++om){
        int obase = wv * 64 + om * 16 + hi * 4;
        f32x4 bia = *(const f32x4*)(b_in + obase);
        const bool isU = (wv < 2);
        #pragma unroll
        for (int lf = 0; lf < 4; ++lf){
            #pragma unroll
            for (int r = 0; r < 4; ++r){
                float v = acc[om][lf][r] + bia[r];
                if (isU) v = silu_f(v);
                ec[(obase + r) * 68 + lf * 16 + lo] = f2bf(v);
            }
        }
    }
    __syncthreads();

    const int r8 = tid >> 5, c32 = tid & 31;
    #pragma unroll
    for (int p = 0; p < 32; ++p){
        int row = r8 + p * 8;                 // 0..255
        int col = c32 * 2;
        uint32 v = *(const uint32*)(ec + row * 68 + col);
        *(uint32*)(UV + ((size_t)(b * 256 + row)) * LL + l0 + col) = v;
    }
}

// ---------------------------------------------------------------------------
// transposing butterfly over lane bits 0..2: afterwards lane holds the total
// of x[lane & 7] over its 8-lane group.
// ---------------------------------------------------------------------------
__device__ __forceinline__ float tbfly8(float (&x)[8], int lane){
    const int t0 = lane & 1, t1 = (lane >> 1) & 1, t2 = (lane >> 2) & 1;
    float y[4], z[2];
    #pragma unroll
    for (int j = 0; j < 4; ++j){
        float keep = t0 ? x[2*j+1] : x[2*j];
        float send = t0 ? x[2*j]   : x[2*j+1];
        y[j] = keep + __shfl_xor(send, 1);
    }
    #pragma unroll
    for (int j = 0; j < 2; ++j){
        float keep = t1 ? y[2*j+1] : y[2*j];
        float send = t1 ? y[2*j]   : y[2*j+1];
        z[j] = keep + __shfl_xor(send, 2);
    }
    float keep = t2 ? z[1] : z[0];
    float send = t2 ? z[0] : z[1];
    return keep + __shfl_xor(send, 4);
}

// ---------------------------------------------------------------------------
// Fused mixer + output GEMM. 512 thr = 8 waves; 32-token tile.
// cl = lane&15 (ch-in-wave), tg = lane>>4 (0..3), c0 = wv*16+cl, m8 = m0+tg*8.
// FIR accumulation in PACKED fp32 (f32x2 -> v_pk_fma_f32, 2 FMAs/inst on
// CDNA) over token pairs; silu/reduction/apply unchanged. 3 barriers.
// grid(288, B) x 512, XCD-chunked swizzle. (512,4): (512,8) forces VGPR=32
// and spills catastrophically (round-15 lesson).
// ---------------------------------------------------------------------------
__global__ __launch_bounds__(512, 4) void k_mixout(const ushort_t* __restrict__ UV,
        const float* __restrict__ dwT, const float* __restrict__ dw_b,
        const ushort_t* __restrict__ WO2, const float* __restrict__ bout2,
        float* __restrict__ out){
    __shared__ __align__(16) float red[8][32][8];       // 8 KB
    __shared__ float tot[32 * 6];                       // ra,rb,rc,rd,C per tok
    __shared__ __align__(16) char ytile[32 * 256];      // 8 KB swizzled

    // XCD-chunked swizzle over 2304 tiles
    const int flat = blockIdx.y * 288 + blockIdx.x;
    const int nf = (flat & 7) * 288 + (flat >> 3);
    const int b  = nf / 288;
    const int m0 = (nf % 288) * 32;

    const int tid  = threadIdx.x;
    const int lane = tid & 63;
    const int wv   = tid >> 6;           // 0..7
    const int cl   = lane & 15;
    const int tg   = lane >> 4;          // 0..3
    const int c0   = wv * 16 + cl;       // channel 0..127
    const int m8   = m0 + tg * 8;
    const int h    = m8 / WW;            // uniform over the 8 tokens
    const int w0g  = m8 - h * WW;

    const ushort_t* vrow = UV + ((size_t)(b * 256 + 128) + c0) * LL + m8;

    // ---- all global loads up front (latency hides under pair-1 compute) ----
    short8 u8  = *(const short8*)(UV + ((size_t)(b * 256) + c0) * LL + m8);
    short8 WBm = *(const short8*)(vrow);
    short8 WA  = *(const short8*)(vrow - 8);
    short8 WC  = *(const short8*)(vrow + 8);
    short8 g8[6];
    bool inb[6];
    #pragma unroll
    for (int r = 0; r < 6; ++r){
        const int dd = (r < 3) ? (r - 3) : (r - 2);
        const int hd = h + dd;
        inb[r] = (hd >= 0) && (hd < HH);
        g8[r] = *(const short8*)(vrow + 96 * dd);   // in ws bounds; gated by inb
    }
    float cw[7];
    #pragma unroll
    for (int j = 0; j < 7; ++j) cw[j] = dwT[j * 128 + c0];
    const float bias = dw_b[c0];

    float ya[8], yb[8], yc[8], yd[8];    // 4 directions, fp32 (no pack)
    float Sa, Qa, Sb, Qb, Sc, Qc, Sd, Qd;

    // ================= PAIR 1: lr + rl (flat H taps, packed-fp32 FIR) =======
    {
        float f[14];
        #pragma unroll
        for (int k = 0; k < 14; ++k){
            int e = 5 + k;                 // elem m8-8+e = m8-3+k
            f[k] = bf2f(e < 8 ? WA[e] : (e < 16 ? WBm[e - 8] : WC[e - 16]));
        }
        if (m8 == 0){ f[0] = 0.f; f[1] = 0.f; f[2] = 0.f; }
        if (m8 == LL - 8){ f[11] = 0.f; f[12] = 0.f; f[13] = 0.f; }
        float qa[8], qb[8];
        #pragma unroll
        for (int i2 = 0; i2 < 4; ++i2){
            f32x2 ca = {bias, bias}, cb = {bias, bias};
            #pragma unroll
            for (int j = 0; j < 7; ++j){
                f32x2 fv  = {f[2 * i2 + j], f[2 * i2 + 1 + j]};
                f32x2 cwj = {cw[j], cw[j]};
                f32x2 cwr = {cw[6 - j], cw[6 - j]};
                ca = __builtin_elementwise_fma(cwj, fv, ca);
                cb = __builtin_elementwise_fma(cwr, fv, cb);
            }
            #pragma unroll
            for (int t = 0; t < 2; ++t){
                int i = 2 * i2 + t;
                float uu = bf2f(u8[i]);
                ya[i] = uu * silu_f(ca[t]);
                yb[i] = uu * silu_f(cb[t]);
                qa[i] = ya[i] * ya[i];
                qb[i] = yb[i] * yb[i];
            }
        }
        Sa = tbfly8(ya, lane); Sa += __shfl_xor(Sa, 8);
        Qa = tbfly8(qa, lane); Qa += __shfl_xor(Qa, 8);
        Sb = tbfly8(yb, lane); Sb += __shfl_xor(Sb, 8);
        Qb = tbfly8(qb, lane); Qb += __shfl_xor(Qb, 8);
    }

    // ================= PAIR 2: tb + bt (vertical taps, packed-fp32 FIR) =====
    {
        f32x2 cafv[4], cbwv[4];
        #pragma unroll
        for (int i2 = 0; i2 < 4; ++i2){
            f32x2 v0 = {bf2f(WBm[2 * i2]), bf2f(WBm[2 * i2 + 1])};
            f32x2 c3 = {cw[3], cw[3]};
            f32x2 bi = {bias, bias};
            cafv[i2] = __builtin_elementwise_fma(c3, v0, bi);
            cbwv[i2] = cafv[i2];
        }
        #pragma unroll
        for (int r = 0; r < 6; ++r){
            const int dd = (r < 3) ? (r - 3) : (r - 2);
            const int j  = dd + 3;
            float gv[8];
            if (inb[r]){
                #pragma unroll
                for (int i = 0; i < 8; ++i) gv[i] = bf2f(g8[r][i]);
            } else {
                const int hd = h + dd;
                const int del = (hd < 0) ? (LL - 1) : (1 - LL);
                #pragma unroll
                for (int i = 0; i < 8; ++i){
                    int q = (w0g + i) * HH + hd;   // col-major flat pos
                    bool ok = (unsigned)q < (unsigned)LL;
                    gv[i] = ok ? bf2f(vrow[96 * dd + del + i]) : 0.f;
                }
            }
            #pragma unroll
            for (int i2 = 0; i2 < 4; ++i2){
                f32x2 gvv = {gv[2 * i2], gv[2 * i2 + 1]};
                f32x2 cwj = {cw[j], cw[j]};
                f32x2 cwr = {cw[6 - j], cw[6 - j]};
                cafv[i2] = __builtin_elementwise_fma(cwj, gvv, cafv[i2]);
                cbwv[i2] = __builtin_elementwise_fma(cwr, gvv, cbwv[i2]);
            }
        }
        float qc[8], qd[8];
        #pragma unroll
        for (int i2 = 0; i2 < 4; ++i2){
            #pragma unroll
            for (int t = 0; t < 2; ++t){
                int i = 2 * i2 + t;
                float uu = bf2f(u8[i]);
                yc[i] = uu * silu_f(cafv[i2][t]);
                yd[i] = uu * silu_f(cbwv[i2][t]);
                qc[i] = yc[i] * yc[i];
                qd[i] = yd[i] * yd[i];
            }
        }
        Sc = tbfly8(yc, lane); Sc += __shfl_xor(Sc, 8);
        Qc = tbfly8(qc, lane); Qc += __shfl_xor(Qc, 8);
        Sd = tbfly8(yd, lane); Sd += __shfl_xor(Sd, 8);
        Qd = tbfly8(qd, lane); Qd += __shfl_xor(Qd, 8);
    }

    // ---- single fused reduction --------------------------------------------
    {
        const int tok32 = tg * 8 + (lane & 7);
        const int halfp = (lane >> 3) & 1;       // duplicate lanes split pairs
        f32x4 stv;
        if (halfp){ stv[0] = Sc; stv[1] = Qc; stv[2] = Sd; stv[3] = Qd; }
        else      { stv[0] = Sa; stv[1] = Qa; stv[2] = Sb; stv[3] = Qb; }
        *(f32x4*)(&red[wv][tok32][halfp * 4]) = stv;
    }
    __syncthreads();
    if (tid < 32){
        f32x4 s0 = {0.f, 0.f, 0.f, 0.f}, s1 = {0.f, 0.f, 0.f, 0.f};
        #pragma unroll
        for (int w2 = 0; w2 < 8; ++w2){
            s0 += *(const f32x4*)(&red[w2][tid][0]);
            s1 += *(const f32x4*)(&red[w2][tid][4]);
        }
        const float inv = 1.f / 128.f;
        float mua = s0[0] * inv, ra = __builtin_amdgcn_rsqf(s0[1] * inv - mua * mua + EPSF);
        float mub = s0[2] * inv, rb = __builtin_amdgcn_rsqf(s0[3] * inv - mub * mub + EPSF);
        float muc = s1[0] * inv, rc = __builtin_amdgcn_rsqf(s1[1] * inv - muc * muc + EPSF);
        float mud = s1[2] * inv, rd = __builtin_amdgcn_rsqf(s1[3] * inv - mud * mud + EPSF);
        float C = mua * ra + mub * rb + muc * rc + mud * rd;
        tot[tid * 6 + 0] = ra; tot[tid * 6 + 1] = rb;
        tot[tid * 6 + 2] = rc; tot[tid * 6 + 3] = rd;
        tot[tid * 6 + 4] = C;
    }
    __syncthreads();

    // ---- prefetch out-GEMM operands (L2-resident; hides under apply) -------
    const int ow = wv;                    // o-range [16*ow, 16*ow+16)
    const int lo = lane & 15, hi = lane >> 4;
    short8 afp[4];
    #pragma unroll
    for (int ks = 0; ks < 4; ++ks)
        afp[ks] = *(const short8*)(WO2 + (size_t)((ow * 4 + ks) * 64 + lane) * 8);
    f32x4 bia = *(const f32x4*)(bout2 + ow * 16 + hi * 4);

    // ---- apply (gamma/beta folded into WO2/bout2) + ytile ------------------
    {
        #pragma unroll
        for (int i = 0; i < 8; ++i){
            int tok = tg * 8 + i;
            f32x2 r01 = *(const f32x2*)(&tot[tok * 6 + 0]);
            f32x2 r23 = *(const f32x2*)(&tot[tok * 6 + 2]);
            float C   = tot[tok * 6 + 4];
            float v = fmaf(ya[i], r01[0], fmaf(yb[i], r01[1],
                      fmaf(yc[i], r23[0], fmaf(yd[i], r23[1], -C))));
            int swz = ((tok & 7) ^ (tok >> 3)) << 4;
            *(ushort_t*)(ytile + tok * 256 + ((c0 * 2) ^ swz)) = f2bf(v);
        }
    }
    __syncthreads();

    // ---- Phase 2: output GEMM (8 waves: wave = 16-o frag x 32 tok) ---------
    const f32x4 zero = {0.f, 0.f, 0.f, 0.f};
    f32x4 acc[2] = {zero, zero};
    #pragma unroll
    for (int ks = 0; ks < 4; ++ks){
        #pragma unroll
        for (int t2 = 0; t2 < 2; ++t2){
            int tok = t2 * 16 + lo;
            int swz = ((tok & 7) ^ (tok >> 3)) << 4;
            short8 bfr = *(const short8*)(ytile + tok * 256 +
                            ((ks * 64 + hi * 16) ^ swz));
            acc[t2] = __builtin_amdgcn_mfma_f32_16x16x32_bf16(afp[ks], bfr, acc[t2], 0, 0, 0);
        }
    }
    {
        #pragma unroll
        for (int t2 = 0; t2 < 2; ++t2){
            int l = m0 + t2 * 16 + lo;
            #pragma unroll
            for (int r = 0; r < 4; ++r){
                int o = ow * 16 + hi * 4 + r;
                out[((size_t)(b * 128 + o)) * LL + l] = acc[t2][r] + bia[r];
            }
        }
    }
}

// ---------------------------------------------------------------------------
extern "C" void kernel_launch(void* const* d_in, const int* in_sizes, int n_in,
                              void* d_out, int out_size, void* d_ws, size_t ws_size,
                              hipStream_t stream) {
    const float* x     = (const float*)d_in[0];
    const float* W_in  = (const float*)d_in[1];
    const float* b_in  = (const float*)d_in[2];
    const float* dw_w  = (const float*)d_in[3];
    const float* dw_b  = (const float*)d_in[4];
    const float* gamma = (const float*)d_in[5];
    const float* beta  = (const float*)d_in[6];
    const float* W_out = (const float*)d_in[7];
    const float* b_out = (const float*)d_in[8];
    float* out = (float*)d_out;

    // ws layout: UV (B,256,L) bf16 | 64B guard | W2 frag | WO2 frag | dwT | bout2
    ushort_t* UV    = (ushort_t*)d_ws;                     // 37,748,736 B
    ushort_t* W2    = UV + (size_t)BB * 256 * LL + 32;     // 256x128 bf16 frag
    ushort_t* WO2   = W2 + 256 * 128;                      // 128x128 bf16 frag
    float*    dwT   = (float*)(WO2 + 128 * 128);           // [7][128] fp32
    float*    bout2 = dwT + 896;                           // [128] fp32

    k_prep<<<128, 256, 0, stream>>>(W_in, W_out, dw_w, gamma, beta, b_out,
                                    W2, WO2, dwT, bout2);

    dim3 gA(LL / 64, BB);
    k_gemmA<<<gA, 256, 0, stream>>>(x, W2, b_in, UV);

    dim3 gM(288, BB);
    k_mixout<<<gM, 512, 0, stream>>>(UV, dwT, dw_b, WO2, bout2, out);
}